// Round 1
// baseline (1743.033 us; speedup 1.0000x reference)
//
#include <hip/hip_runtime.h>

#define KNB 19

__device__ __forceinline__ float leaky_f(float z) { return fmaxf(z, 0.2f * z); }

// ---------------------------------------------------------------------------
// Weight transpose: W[cout][KC] -> Wt[KC][cout]
// ---------------------------------------------------------------------------
__global__ void transpose_w(const float* __restrict__ W, float* __restrict__ Wt,
                            int KC, int COUT) {
    int idx = blockIdx.x * 256 + threadIdx.x;
    if (idx < KC * COUT) {
        int i = idx / COUT;
        int o = idx - i * COUT;
        Wt[idx] = W[o * KC + i];
    }
}

// ---------------------------------------------------------------------------
// Conv kernel: out[v,o,b] = sum_{k,ci} bnleaky(x[n[v,k],ci,b]) * W[o, k*CIN+ci] + bias[o]
// Also accumulates per-channel sum / sumsq (BN stats of OUTPUT) into ostats.
// Layout: activations [V][C][B=4] fp32, float4 over B. Wt: [KC][COUT].
// Block: 256 threads = TILE_V vertices x (COUT/4) output-groups.
// ---------------------------------------------------------------------------
template <int CIN, int COUT, int TILE_V, int IC, bool APPLY_BN>
__global__ __launch_bounds__(256) void conv_kernel(
    const float* __restrict__ xin, const int* __restrict__ neigh,
    const float* __restrict__ Wt, const float* __restrict__ bias,
    const float* __restrict__ pstats, const float* __restrict__ pg,
    const float* __restrict__ pb, float invN,
    float* __restrict__ y, float* __restrict__ ostats, int V) {
    constexpr int KC = KNB * CIN;
    constexpr int OG = COUT / 4;
    static_assert(TILE_V * OG == 256, "bad config");

    __shared__ int sh_n[TILE_V * KNB];
    __shared__ float4 sh_x[TILE_V * (IC + 1)];   // +1 f4 row pad: bank rotation
    __shared__ float sh_sum[COUT];
    __shared__ float sh_ssq[COUT];
    __shared__ float bn_a[APPLY_BN ? CIN : 1];
    __shared__ float bn_c[APPLY_BN ? CIN : 1];

    const int tid = threadIdx.x;
    const int v0 = blockIdx.x * TILE_V;

    for (int t = tid; t < TILE_V * KNB; t += 256) {
        int v = v0 + t / KNB;
        sh_n[t] = (v < V) ? neigh[v * KNB + t % KNB] : -1;
    }
    if (tid < COUT) { sh_sum[tid] = 0.f; sh_ssq[tid] = 0.f; }
    if constexpr (APPLY_BN) {
        if (tid < CIN) {
            float s = pstats[tid], ss = pstats[CIN + tid];
            float mu = s * invN;
            float var = fmaf(ss, invN, -mu * mu);
            float aa = pg[tid] * rsqrtf(var + 1e-5f);
            bn_a[tid] = aa;
            bn_c[tid] = fmaf(-mu, aa, pb[tid]);
        }
    }

    const int vt = tid / OG;
    const int og = tid - vt * OG;
    float acc[4][4];
#pragma unroll
    for (int j = 0; j < 4; ++j)
#pragma unroll
        for (int b = 0; b < 4; ++b) acc[j][b] = 0.f;

    const float4* __restrict__ x4 = (const float4*)xin;
    const float4* __restrict__ Wt4 = (const float4*)Wt;

    auto gather_at = [&](int gvt, int ti, int gi) {
        int k = gi / CIN;
        int ci = gi - k * CIN;
        int n = sh_n[gvt * KNB + k];
        float4 v;
        if (n >= 0) {
            v = x4[(size_t)n * CIN + ci];
            if constexpr (APPLY_BN) {
                float aa = bn_a[ci], cc = bn_c[ci];
                v.x = leaky_f(fmaf(aa, v.x, cc));
                v.y = leaky_f(fmaf(aa, v.y, cc));
                v.z = leaky_f(fmaf(aa, v.z, cc));
                v.w = leaky_f(fmaf(aa, v.w, cc));
            }
        } else {
            v = make_float4(0.f, 0.f, 0.f, 0.f);
        }
        sh_x[gvt * (IC + 1) + ti] = v;
    };

    __syncthreads();

    for (int i0 = 0; i0 < KC; i0 += IC) {
        const int rem = (KC - i0 < IC) ? (KC - i0) : IC;
        if (rem == IC) {  // static divisor path (compiler magic-mul / shifts)
            for (int t = tid; t < TILE_V * IC; t += 256) {
                int gvt = t / IC;
                int ti = t - gvt * IC;
                gather_at(gvt, ti, i0 + ti);
            }
        } else {
            for (int t = tid; t < TILE_V * rem; t += 256) {
                int gvt = t / rem;
                int ti = t - gvt * rem;
                gather_at(gvt, ti, i0 + ti);
            }
        }
        __syncthreads();

        const float4* wp = Wt4 + (size_t)i0 * OG + og;
        const float4* xp = &sh_x[vt * (IC + 1)];
#pragma unroll 4
        for (int i = 0; i < rem; ++i, wp += OG) {
            float4 a = xp[i];
            float4 w = *wp;
            acc[0][0] = fmaf(a.x, w.x, acc[0][0]);
            acc[0][1] = fmaf(a.y, w.x, acc[0][1]);
            acc[0][2] = fmaf(a.z, w.x, acc[0][2]);
            acc[0][3] = fmaf(a.w, w.x, acc[0][3]);
            acc[1][0] = fmaf(a.x, w.y, acc[1][0]);
            acc[1][1] = fmaf(a.y, w.y, acc[1][1]);
            acc[1][2] = fmaf(a.z, w.y, acc[1][2]);
            acc[1][3] = fmaf(a.w, w.y, acc[1][3]);
            acc[2][0] = fmaf(a.x, w.z, acc[2][0]);
            acc[2][1] = fmaf(a.y, w.z, acc[2][1]);
            acc[2][2] = fmaf(a.z, w.z, acc[2][2]);
            acc[2][3] = fmaf(a.w, w.z, acc[2][3]);
            acc[3][0] = fmaf(a.x, w.w, acc[3][0]);
            acc[3][1] = fmaf(a.y, w.w, acc[3][1]);
            acc[3][2] = fmaf(a.z, w.w, acc[3][2]);
            acc[3][3] = fmaf(a.w, w.w, acc[3][3]);
        }
        __syncthreads();
    }

    const int v = v0 + vt;
    if (v < V) {
        float4* y4 = (float4*)y;
#pragma unroll
        for (int j = 0; j < 4; ++j) {
            float bj = bias[og * 4 + j];
            float4 r = make_float4(acc[j][0] + bj, acc[j][1] + bj,
                                   acc[j][2] + bj, acc[j][3] + bj);
            y4[(size_t)v * COUT + og * 4 + j] = r;
            float s = (r.x + r.y) + (r.z + r.w);
            float q = (r.x * r.x + r.y * r.y) + (r.z * r.z + r.w * r.w);
            atomicAdd(&sh_sum[og * 4 + j], s);
            atomicAdd(&sh_ssq[og * 4 + j], q);
        }
    }
    __syncthreads();
    if (tid < COUT) {
        atomicAdd(&ostats[tid], sh_sum[tid]);
        atomicAdd(&ostats[COUT + tid], sh_ssq[tid]);
    }
}

// ---------------------------------------------------------------------------
// Mean-pool over K-neighborhoods, applying producer's BN+leaky on the fly.
// ---------------------------------------------------------------------------
__global__ __launch_bounds__(256) void pool_kernel(
    const float* __restrict__ x, const int* __restrict__ neigh,
    const float* __restrict__ stats, const float* __restrict__ gam,
    const float* __restrict__ bet, float invN,
    float* __restrict__ out, int VP, int C) {
    int idx = blockIdx.x * 256 + threadIdx.x;
    if (idx >= VP * C) return;
    int vp = idx / C;
    int c = idx - vp * C;
    float s = stats[c], ss = stats[C + c];
    float mu = s * invN;
    float var = fmaf(ss, invN, -mu * mu);
    float aa = gam[c] * rsqrtf(var + 1e-5f);
    float cc = fmaf(-mu, aa, bet[c]);
    const float4* x4 = (const float4*)x;
    float4 acc = make_float4(0.f, 0.f, 0.f, 0.f);
    for (int k = 0; k < KNB; ++k) {
        int n = neigh[vp * KNB + k];
        float4 v = x4[(size_t)n * C + c];
        acc.x += leaky_f(fmaf(aa, v.x, cc));
        acc.y += leaky_f(fmaf(aa, v.y, cc));
        acc.z += leaky_f(fmaf(aa, v.z, cc));
        acc.w += leaky_f(fmaf(aa, v.w, cc));
    }
    const float r = 1.f / (float)KNB;
    float4 o = make_float4(acc.x * r, acc.y * r, acc.z * r, acc.w * r);
    ((float4*)out)[idx] = o;
}

// ---------------------------------------------------------------------------
// FC partial: dot(bnleaky(x[642,256,4]) flattened (v,c), wfc) per batch b.
// ---------------------------------------------------------------------------
__global__ __launch_bounds__(256) void fc_partial(
    const float* __restrict__ x, const float* __restrict__ wfc,
    const float* __restrict__ stats, const float* __restrict__ gam,
    const float* __restrict__ bet, float invN, float* __restrict__ acc_out) {
    __shared__ float sh[4];
    if (threadIdx.x < 4) sh[threadIdx.x] = 0.f;
    __syncthreads();
    float p0 = 0.f, p1 = 0.f, p2 = 0.f, p3 = 0.f;
    const float4* x4 = (const float4*)x;
    for (int idx = blockIdx.x * 256 + threadIdx.x; idx < 642 * 256;
         idx += gridDim.x * 256) {
        int c = idx & 255;
        float s = stats[c], ss = stats[256 + c];
        float mu = s * invN;
        float var = fmaf(ss, invN, -mu * mu);
        float aa = gam[c] * rsqrtf(var + 1e-5f);
        float cc = fmaf(-mu, aa, bet[c]);
        float w = wfc[idx];
        float4 v = x4[idx];
        p0 = fmaf(w, leaky_f(fmaf(aa, v.x, cc)), p0);
        p1 = fmaf(w, leaky_f(fmaf(aa, v.y, cc)), p1);
        p2 = fmaf(w, leaky_f(fmaf(aa, v.z, cc)), p2);
        p3 = fmaf(w, leaky_f(fmaf(aa, v.w, cc)), p3);
    }
    atomicAdd(&sh[0], p0);
    atomicAdd(&sh[1], p1);
    atomicAdd(&sh[2], p2);
    atomicAdd(&sh[3], p3);
    __syncthreads();
    if (threadIdx.x < 4) atomicAdd(&acc_out[threadIdx.x], sh[threadIdx.x]);
}

__global__ void fc_finalize(const float* __restrict__ acc,
                            const float* __restrict__ m,
                            const float* __restrict__ wm,
                            const float* __restrict__ bm,
                            const float* __restrict__ wfc,
                            const float* __restrict__ bfc,
                            float* __restrict__ out) {
    int b = threadIdx.x;
    if (b < 4) {
        float mv = m[b];
        float s = 0.f;
#pragma unroll
        for (int j = 0; j < 4; ++j) {
            float mm = fmaxf(fmaf(mv, wm[j], bm[j]), 0.f);  // relu(conv1d 1->4)
            s = fmaf(mm, wfc[642 * 256 + j], s);
        }
        out[b] = acc[b] + s + bfc[0];
    }
}

// ---------------------------------------------------------------------------
// Workspace layout (float offsets)
// ---------------------------------------------------------------------------
static constexpr size_t A_OFF = 0;                    // 40962*32*4 = 5243136 floats
static constexpr size_t B_OFF = 5243136;
static constexpr size_t ST_OFF = 10486272;            // 8 x 512 floats of BN stats
static constexpr size_t FC_OFF = ST_OFF + 8 * 512;    // 4 floats fc accumulator
static constexpr size_t WT_OFF = FC_OFF + 4;          // transposed weights

extern "C" void kernel_launch(void* const* d_in, const int* in_sizes, int n_in,
                              void* d_out, int out_size, void* d_ws, size_t ws_size,
                              hipStream_t stream) {
    const float* x = (const float*)d_in[0];
    const float* m = (const float*)d_in[1];
    const int* n0 = (const int*)d_in[2];
    const int* n1 = (const int*)d_in[3];
    const int* n2 = (const int*)d_in[4];
    // d_in[5] = n3 (unused: level-4 conv uses n3)
    const int* n3 = (const int*)d_in[5];

    const float* W[8]  = {(const float*)d_in[6],  (const float*)d_in[10],
                          (const float*)d_in[14], (const float*)d_in[18],
                          (const float*)d_in[22], (const float*)d_in[26],
                          (const float*)d_in[30], (const float*)d_in[34]};
    const float* Bi[8] = {(const float*)d_in[7],  (const float*)d_in[11],
                          (const float*)d_in[15], (const float*)d_in[19],
                          (const float*)d_in[23], (const float*)d_in[27],
                          (const float*)d_in[31], (const float*)d_in[35]};
    const float* G[8]  = {(const float*)d_in[8],  (const float*)d_in[12],
                          (const float*)d_in[16], (const float*)d_in[20],
                          (const float*)d_in[24], (const float*)d_in[28],
                          (const float*)d_in[32], (const float*)d_in[36]};
    const float* E[8]  = {(const float*)d_in[9],  (const float*)d_in[13],
                          (const float*)d_in[17], (const float*)d_in[21],
                          (const float*)d_in[25], (const float*)d_in[29],
                          (const float*)d_in[33], (const float*)d_in[37]};
    const float* wm  = (const float*)d_in[38];
    const float* bm  = (const float*)d_in[39];
    const float* wfc = (const float*)d_in[40];
    const float* bfc = (const float*)d_in[41];

    float* ws = (float*)d_ws;
    float* A = ws + A_OFF;
    float* Bbuf = ws + B_OFF;
    float* st = ws + ST_OFF;
    float* fcacc = ws + FC_OFF;

    // Transposed-weight offsets (cumulative; sizes = KC*COUT)
    static const size_t wt_off[8] = {
        WT_OFF,              WT_OFF + 2432,       WT_OFF + 21888,
        WT_OFF + 60800,      WT_OFF + 138624,     WT_OFF + 294272,
        WT_OFF + 605568,     WT_OFF + 1228160};
    static const int KCs[8]   = {76, 608, 608, 1216, 1216, 2432, 2432, 4864};
    static const int COUTs[8] = {32, 32, 64, 64, 128, 128, 256, 256};

    // zero BN stat accumulators + fc accumulator
    hipMemsetAsync(st, 0, (8 * 512 + 4) * sizeof(float), stream);

    for (int j = 0; j < 8; ++j) {
        int nelem = KCs[j] * COUTs[j];
        transpose_w<<<(nelem + 255) / 256, 256, 0, stream>>>(W[j], ws + wt_off[j],
                                                             KCs[j], COUTs[j]);
    }

    const float iN1 = 1.f / (40962.f * 4.f);
    const float iN2 = 1.f / (10242.f * 4.f);
    const float iN3 = 1.f / (2562.f * 4.f);
    const float iN4 = 1.f / (642.f * 4.f);

    // Level 1 (V=40962)
    conv_kernel<4, 32, 32, 76, false><<<1281, 256, 0, stream>>>(
        x, n0, ws + wt_off[0], Bi[0], nullptr, nullptr, nullptr, 0.f,
        A, st + 0 * 512, 40962);
    conv_kernel<32, 32, 32, 64, true><<<1281, 256, 0, stream>>>(
        A, n0, ws + wt_off[1], Bi[1], st + 0 * 512, G[0], E[0], iN1,
        Bbuf, st + 1 * 512, 40962);
    pool_kernel<<<1281, 256, 0, stream>>>(Bbuf, n0, st + 1 * 512, G[1], E[1], iN1,
                                          A, 10242, 32);
    // Level 2 (V=10242)
    conv_kernel<32, 64, 16, 128, false><<<641, 256, 0, stream>>>(
        A, n1, ws + wt_off[2], Bi[2], nullptr, nullptr, nullptr, 0.f,
        Bbuf, st + 2 * 512, 10242);
    conv_kernel<64, 64, 16, 192, true><<<641, 256, 0, stream>>>(
        Bbuf, n1, ws + wt_off[3], Bi[3], st + 2 * 512, G[2], E[2], iN2,
        A, st + 3 * 512, 10242);
    pool_kernel<<<641, 256, 0, stream>>>(A, n1, st + 3 * 512, G[3], E[3], iN2,
                                         Bbuf, 2562, 64);
    // Level 3 (V=2562)
    conv_kernel<64, 128, 8, 256, false><<<321, 256, 0, stream>>>(
        Bbuf, n2, ws + wt_off[4], Bi[4], nullptr, nullptr, nullptr, 0.f,
        A, st + 4 * 512, 2562);
    conv_kernel<128, 128, 8, 448, true><<<321, 256, 0, stream>>>(
        A, n2, ws + wt_off[5], Bi[5], st + 4 * 512, G[4], E[4], iN3,
        Bbuf, st + 5 * 512, 2562);
    pool_kernel<<<321, 256, 0, stream>>>(Bbuf, n2, st + 5 * 512, G[5], E[5], iN3,
                                         A, 642, 128);
    // Level 4 (V=642)
    conv_kernel<128, 256, 4, 896, false><<<161, 256, 0, stream>>>(
        A, n3, ws + wt_off[6], Bi[6], nullptr, nullptr, nullptr, 0.f,
        Bbuf, st + 6 * 512, 642);
    conv_kernel<256, 256, 4, 896, true><<<161, 256, 0, stream>>>(
        Bbuf, n3, ws + wt_off[7], Bi[7], st + 6 * 512, G[6], E[6], iN4,
        A, st + 7 * 512, 642);
    // FC
    fc_partial<<<256, 256, 0, stream>>>(A, wfc, st + 7 * 512, G[7], E[7], iN4,
                                        fcacc);
    fc_finalize<<<1, 64, 0, stream>>>(fcacc, m, wm, bm, wfc, bfc,
                                      (float*)d_out);
}

// Round 2
// 657.610 us; speedup vs baseline: 2.6506x; 2.6506x over previous
//
#include <hip/hip_runtime.h>

typedef short bf16x8 __attribute__((ext_vector_type(8)));
typedef float f32x4 __attribute__((ext_vector_type(4)));

__device__ __forceinline__ float leaky_f(float z) { return fmaxf(z, 0.2f * z); }
__device__ __forceinline__ unsigned short f2b(float f) {
    unsigned u = __float_as_uint(f);
    return (unsigned short)((u + 0x7fffu + ((u >> 16) & 1u)) >> 16);  // RTNE
}
__device__ __forceinline__ float b2f(unsigned short h) {
    return __uint_as_float(((unsigned)h) << 16);
}

// ---------------------------------------------------------------------------
// x [V][4][B=4] fp32 -> bf16 planes [B][V][4]
// ---------------------------------------------------------------------------
__global__ __launch_bounds__(256) void cast_x(const float* __restrict__ x,
                                              unsigned short* __restrict__ out, int V) {
    int idx = blockIdx.x * 256 + threadIdx.x;  // over V*4 (v*4+ci)
    int b = blockIdx.y;
    if (idx < V * 4) out[(size_t)b * V * 4 + idx] = f2b(x[(size_t)idx * 4 + b]);
}

// ---------------------------------------------------------------------------
// W [COUT][KC] fp32 -> bf16 packed B-fragments:
// wp[((chunk*NT + nt)*64 + lane)*8 + j] = W[nt*16+(lane&15)][chunk*32+(lane>>4)*8+j]
// ---------------------------------------------------------------------------
__global__ __launch_bounds__(256) void prepack_w(const float* __restrict__ W,
                                                 unsigned short* __restrict__ wp,
                                                 int KC, int NT, int total) {
    int idx = blockIdx.x * 256 + threadIdx.x;
    if (idx >= total) return;
    int j = idx & 7, lane = (idx >> 3) & 63, q = idx >> 9;
    int nt = q % NT, chunk = q / NT;
    int kc = chunk * 32 + (lane >> 4) * 8 + j;
    int cout = nt * 16 + (lane & 15);
    float v = (kc < KC) ? W[(size_t)cout * KC + kc] : 0.f;
    wp[idx] = f2b(v);
}

// ---------------------------------------------------------------------------
// MFMA conv, CIN in {32,64,128,256}: y[b][v][cout] = sum_gi act[b][n[v][gi/CIN]][gi%CIN]*W[cout][gi]
// wave = 16 vertices x (NG*16 couts) for one batch plane; K chunked by 32.
// ---------------------------------------------------------------------------
template <int CIN, int COUT, int NG>
__global__ __launch_bounds__(256) void conv_mfma(
    const unsigned short* __restrict__ actb, const int* __restrict__ neigh,
    const unsigned short* __restrict__ wp, float* __restrict__ y, int V) {
    constexpr int LOGC = (CIN == 32) ? 5 : (CIN == 64) ? 6 : (CIN == 128) ? 7 : 8;
    constexpr int KCH = (19 * CIN) / 32;
    constexpr int NT = COUT / 16;
    constexpr int NGRP = NT / NG;
    constexpr int LNG = (NGRP == 1) ? 0 : (NGRP == 2) ? 1 : 2;
    __shared__ int shn[4 * 304];
    const int lane = threadIdx.x & 63;
    const int wib = threadIdx.x >> 6;
    const int gwid = blockIdx.x * 4 + wib;
    const int VT = (V + 15) >> 4;
    if (gwid >= VT * 4 * NGRP) return;
    const int b = gwid & 3;
    const int rest = gwid >> 2;
    const int ng = rest & (NGRP - 1);
    const int vt = rest >> LNG;
    const int v0 = vt * 16;
    const int m = lane & 15, quad = lane >> 4;
    int* sn = shn + wib * 304;
    {
        const int lim = V * 19 - 1;
        for (int t = lane; t < 304; t += 64) {
            int src = v0 * 19 + t;
            sn[t] = neigh[src < lim ? src : lim];
        }
    }
    const unsigned short* plane = actb + (size_t)b * V * CIN;
    const unsigned short* wl = wp + ((size_t)(ng * NG) * 64 + lane) * 8;

    f32x4 acc[NG];
#pragma unroll
    for (int t = 0; t < NG; ++t) acc[t] = (f32x4){0.f, 0.f, 0.f, 0.f};

    auto loadA = [&](int ch) -> bf16x8 {
        int k_nb = (ch * 32) >> LOGC;                 // wave-uniform
        int ci = ((ch * 32) & (CIN - 1)) + quad * 8;  // < CIN
        int n = sn[m * 19 + k_nb];
        return *(const bf16x8*)(plane + (size_t)n * CIN + ci);
    };

    bf16x8 aC = loadA(0);
    bf16x8 bC[NG];
#pragma unroll
    for (int t = 0; t < NG; ++t) bC[t] = *(const bf16x8*)(wl + (size_t)t * 512);

    for (int ch = 0; ch < KCH; ++ch) {
        bf16x8 aN = aC;
        bf16x8 bN[NG];
#pragma unroll
        for (int t = 0; t < NG; ++t) bN[t] = bC[t];
        if (ch + 1 < KCH) {
            aN = loadA(ch + 1);
            const unsigned short* wc = wl + (size_t)(ch + 1) * NT * 512;
#pragma unroll
            for (int t = 0; t < NG; ++t) bN[t] = *(const bf16x8*)(wc + (size_t)t * 512);
        }
#pragma unroll
        for (int t = 0; t < NG; ++t)
            acc[t] = __builtin_amdgcn_mfma_f32_16x16x32_bf16(aC, bC[t], acc[t], 0, 0, 0);
        aC = aN;
#pragma unroll
        for (int t = 0; t < NG; ++t) bC[t] = bN[t];
    }

    float* yb = y + (size_t)b * V * COUT;
#pragma unroll
    for (int r = 0; r < 4; ++r) {
        int v = v0 + quad * 4 + r;  // C/D: row=(lane>>4)*4+r, col=lane&15
        if (v < V) {
#pragma unroll
            for (int t = 0; t < NG; ++t) {
                int cout = (ng * NG + t) * 16 + (lane & 15);
                yb[(size_t)v * COUT + cout] = acc[t][r];
            }
        }
    }
}

// ---------------------------------------------------------------------------
// conv1_1: CIN=4, KC=76 (padded to 96 -> 3 chunks), COUT=32 (NT=2, NG=2)
// ---------------------------------------------------------------------------
__global__ __launch_bounds__(256) void conv1_mfma(
    const unsigned short* __restrict__ actb, const int* __restrict__ neigh,
    const unsigned short* __restrict__ wp, float* __restrict__ y, int V) {
    __shared__ int shn[4 * 304];
    const int lane = threadIdx.x & 63;
    const int wib = threadIdx.x >> 6;
    const int gwid = blockIdx.x * 4 + wib;
    const int VT = (V + 15) >> 4;
    if (gwid >= VT * 4) return;
    const int b = gwid & 3;
    const int vt = gwid >> 2;
    const int v0 = vt * 16;
    const int m = lane & 15, quad = lane >> 4;
    int* sn = shn + wib * 304;
    {
        const int lim = V * 19 - 1;
        for (int t = lane; t < 304; t += 64) {
            int src = v0 * 19 + t;
            sn[t] = neigh[src < lim ? src : lim];
        }
    }
    const unsigned short* plane = actb + (size_t)b * V * 4;
    const unsigned short* wl = wp + (size_t)lane * 8;

    f32x4 acc[2] = {(f32x4){0.f, 0.f, 0.f, 0.f}, (f32x4){0.f, 0.f, 0.f, 0.f}};
    for (int ch = 0; ch < 3; ++ch) {
        int gi0 = ch * 32 + quad * 8;
        int k0 = gi0 >> 2;  // 8 elems span neighbors k0, k0+1 (4 ci each)
        union { unsigned u[4]; bf16x8 v; } w;
        w.u[0] = w.u[1] = w.u[2] = w.u[3] = 0u;
        if (k0 < 19) {
            const unsigned* p = (const unsigned*)(plane + (size_t)sn[m * 19 + k0] * 4);
            w.u[0] = p[0]; w.u[1] = p[1];
        }
        if (k0 + 1 < 19) {
            const unsigned* p = (const unsigned*)(plane + (size_t)sn[m * 19 + k0 + 1] * 4);
            w.u[2] = p[0]; w.u[3] = p[1];
        }
#pragma unroll
        for (int t = 0; t < 2; ++t) {
            bf16x8 bf = *(const bf16x8*)(wl + (size_t)ch * 1024 + (size_t)t * 512);
            acc[t] = __builtin_amdgcn_mfma_f32_16x16x32_bf16(w.v, bf, acc[t], 0, 0, 0);
        }
    }
    float* yb = y + (size_t)b * V * 32;
#pragma unroll
    for (int r = 0; r < 4; ++r) {
        int v = v0 + quad * 4 + r;
        if (v < V) {
#pragma unroll
            for (int t = 0; t < 2; ++t)
                yb[(size_t)v * 32 + t * 16 + (lane & 15)] = acc[t][r];
        }
    }
}

// ---------------------------------------------------------------------------
// Per-channel sum / sumsq of y [rows][C] -> st[0..C-1]=sum, st[C..2C-1]=ssq
// ---------------------------------------------------------------------------
template <int C>
__global__ __launch_bounds__(256) void stats_kernel(const float* __restrict__ y,
                                                    float* __restrict__ st, int rows) {
    constexpr int LOGC = (C == 32) ? 5 : (C == 64) ? 6 : (C == 128) ? 7 : 8;
    __shared__ float ss[2 * C];
    int tid = threadIdx.x;
    for (int i = tid; i < 2 * C; i += 256) ss[i] = 0.f;
    __syncthreads();
    int c = tid & (C - 1);
    const int rpb = 256 >> LOGC;
    float s = 0.f, q = 0.f;
    for (int r = blockIdx.x * rpb + (tid >> LOGC); r < rows; r += gridDim.x * rpb) {
        float v = y[(size_t)r * C + c];
        s += v;
        q = fmaf(v, v, q);
    }
    atomicAdd(&ss[c], s);
    atomicAdd(&ss[C + c], q);
    __syncthreads();
    for (int i = tid; i < 2 * C; i += 256) atomicAdd(&st[i], ss[i]);
}

// ---------------------------------------------------------------------------
// bnleaky(y) -> bf16 planes (same [B][V][C] layout), vectorized by 4 channels
// ---------------------------------------------------------------------------
template <int C>
__global__ __launch_bounds__(256) void finalize_kernel(
    const float* __restrict__ y, const float* __restrict__ st,
    const float* __restrict__ g, const float* __restrict__ be, float invN,
    unsigned short* __restrict__ out, int total4) {
    int idx = blockIdx.x * 256 + threadIdx.x;
    if (idx >= total4) return;
    int c0 = (idx * 4) & (C - 1);
    float4 yv = ((const float4*)y)[idx];
    float4 s4 = *(const float4*)(st + c0);
    float4 q4 = *(const float4*)(st + C + c0);
    float4 g4 = *(const float4*)(g + c0);
    float4 b4 = *(const float4*)(be + c0);
    auto bn1 = [&](float v, float s, float q, float gg, float bb) {
        float mu = s * invN;
        float var = fmaf(q, invN, -mu * mu);
        float a = gg * rsqrtf(var + 1e-5f);
        return leaky_f(fmaf(a, v, fmaf(-mu, a, bb)));
    };
    float o0 = bn1(yv.x, s4.x, q4.x, g4.x, b4.x);
    float o1 = bn1(yv.y, s4.y, q4.y, g4.y, b4.y);
    float o2 = bn1(yv.z, s4.z, q4.z, g4.z, b4.z);
    float o3 = bn1(yv.w, s4.w, q4.w, g4.w, b4.w);
    unsigned r0 = (unsigned)f2b(o0) | ((unsigned)f2b(o1) << 16);
    unsigned r1 = (unsigned)f2b(o2) | ((unsigned)f2b(o3) << 16);
    ((uint2*)out)[idx] = make_uint2(r0, r1);
}

// ---------------------------------------------------------------------------
// Mean-pool bf16 planes [B][Vin][C] -> [B][VP][C]
// ---------------------------------------------------------------------------
template <int C>
__global__ __launch_bounds__(256) void pool_kernel(const unsigned short* __restrict__ in,
                                                   const int* __restrict__ neigh,
                                                   unsigned short* __restrict__ out,
                                                   int Vin, int VP) {
    constexpr int LOGC4 = (C == 32) ? 3 : (C == 64) ? 4 : 5;
    int idx = blockIdx.x * 256 + threadIdx.x;
    int b = blockIdx.y;
    if (idx >= VP * (C / 4)) return;
    int c4 = idx & ((C / 4) - 1);
    int vp = idx >> LOGC4;
    const unsigned short* pin = in + (size_t)b * Vin * C;
    float a0 = 0.f, a1 = 0.f, a2 = 0.f, a3 = 0.f;
    for (int k = 0; k < 19; ++k) {
        int n = neigh[vp * 19 + k];
        uint2 d = *(const uint2*)(pin + (size_t)n * C + c4 * 4);
        a0 += b2f((unsigned short)(d.x & 0xffff));
        a1 += b2f((unsigned short)(d.x >> 16));
        a2 += b2f((unsigned short)(d.y & 0xffff));
        a3 += b2f((unsigned short)(d.y >> 16));
    }
    const float r = 1.f / 19.f;
    unsigned r0 = (unsigned)f2b(a0 * r) | ((unsigned)f2b(a1 * r) << 16);
    unsigned r1 = (unsigned)f2b(a2 * r) | ((unsigned)f2b(a3 * r) << 16);
    ((uint2*)(out + (size_t)b * VP * C))[idx] = make_uint2(r0, r1);
}

// ---------------------------------------------------------------------------
// FC over bnleaky(y4_2) [4][642][256] with wfc[v*256+c]; partial atomics
// ---------------------------------------------------------------------------
__global__ __launch_bounds__(256) void fc_partial(
    const float* __restrict__ y, const float* __restrict__ wfc,
    const float* __restrict__ st, const float* __restrict__ g,
    const float* __restrict__ be, float invN, float* __restrict__ fcacc) {
    __shared__ float sh[4];
    int tid = threadIdx.x;
    if (tid < 4) sh[tid] = 0.f;
    __syncthreads();
    float p0 = 0.f, p1 = 0.f, p2 = 0.f, p3 = 0.f;
    const int VC = 642 * 256;
    for (int idx = blockIdx.x * 256 + tid; idx < VC; idx += gridDim.x * 256) {
        int c = idx & 255;
        float s = st[c], q = st[256 + c];
        float mu = s * invN;
        float var = fmaf(q, invN, -mu * mu);
        float a = g[c] * rsqrtf(var + 1e-5f);
        float cc = fmaf(-mu, a, be[c]);
        float w = wfc[idx];
        p0 = fmaf(w, leaky_f(fmaf(a, y[idx], cc)), p0);
        p1 = fmaf(w, leaky_f(fmaf(a, y[VC + idx], cc)), p1);
        p2 = fmaf(w, leaky_f(fmaf(a, y[2 * VC + idx], cc)), p2);
        p3 = fmaf(w, leaky_f(fmaf(a, y[3 * VC + idx], cc)), p3);
    }
    atomicAdd(&sh[0], p0);
    atomicAdd(&sh[1], p1);
    atomicAdd(&sh[2], p2);
    atomicAdd(&sh[3], p3);
    __syncthreads();
    if (tid < 4) atomicAdd(&fcacc[tid], sh[tid]);
}

__global__ void fc_finalize(const float* __restrict__ acc, const float* __restrict__ m,
                            const float* __restrict__ wm, const float* __restrict__ bm,
                            const float* __restrict__ wfc, const float* __restrict__ bfc,
                            float* __restrict__ out) {
    int b = threadIdx.x;
    if (b < 4) {
        float mv = m[b];
        float s = 0.f;
#pragma unroll
        for (int j = 0; j < 4; ++j) {
            float mm = fmaxf(fmaf(mv, wm[j], bm[j]), 0.f);
            s = fmaf(mm, wfc[642 * 256 + j], s);
        }
        out[b] = acc[b] + s + bfc[0];
    }
}

// ---------------------------------------------------------------------------
// Workspace layout (bytes):
//  Y     @ 0          : 5,243,136 fp32 (max 4*40962*32)      = 20,972,544 B
//  P     @ 20,972,544 : 5,243,136 bf16                        = 10,486,272 B
//  Q     @ 31,458,816 : 5,243,136 bf16                        = 10,486,272 B
//  st    @ 41,945,088 : 8*512 fp32 + fcacc 4 fp32             =     16,400 B
//  WP    @ 41,961,488 : 2,473,984 bf16 packed weights         =  4,947,968 B
// ---------------------------------------------------------------------------
extern "C" void kernel_launch(void* const* d_in, const int* in_sizes, int n_in,
                              void* d_out, int out_size, void* d_ws, size_t ws_size,
                              hipStream_t stream) {
    const float* x = (const float*)d_in[0];
    const float* m = (const float*)d_in[1];
    const int* n0 = (const int*)d_in[2];
    const int* n1 = (const int*)d_in[3];
    const int* n2 = (const int*)d_in[4];
    const int* n3 = (const int*)d_in[5];

    const float* W[8]  = {(const float*)d_in[6],  (const float*)d_in[10],
                          (const float*)d_in[14], (const float*)d_in[18],
                          (const float*)d_in[22], (const float*)d_in[26],
                          (const float*)d_in[30], (const float*)d_in[34]};
    // biases are all zeros in setup (b*_*), and reference adds them before BN;
    // BN subtracts the mean so a constant per-channel bias cancels EXCEPT it
    // shifts mu -- but mu is computed from y INCLUDING bias, so (y+b)-mean(y+b)
    // == y-mean(y). Bias is therefore a no-op through BN. Still, keep stats
    // exact: bias only shifts sum, variance unchanged -> BN output identical.
    const float* G[8]  = {(const float*)d_in[8],  (const float*)d_in[12],
                          (const float*)d_in[16], (const float*)d_in[20],
                          (const float*)d_in[24], (const float*)d_in[28],
                          (const float*)d_in[32], (const float*)d_in[36]};
    const float* E[8]  = {(const float*)d_in[9],  (const float*)d_in[13],
                          (const float*)d_in[17], (const float*)d_in[21],
                          (const float*)d_in[25], (const float*)d_in[29],
                          (const float*)d_in[33], (const float*)d_in[37]};
    const float* wm  = (const float*)d_in[38];
    const float* bm  = (const float*)d_in[39];
    const float* wfc = (const float*)d_in[40];
    const float* bfc = (const float*)d_in[41];

    char* wsb = (char*)d_ws;
    float* Y = (float*)wsb;
    unsigned short* P = (unsigned short*)(wsb + 20972544);
    unsigned short* Q = (unsigned short*)(wsb + 31458816);
    float* st = (float*)(wsb + 41945088);
    float* fcacc = st + 4096;
    unsigned short* WP = (unsigned short*)(wsb + 41961488);

    static const int wp_off[8] = {0, 3072, 22528, 61440, 139264, 294912, 606208, 1228800};
    static const int KCs[8]    = {76, 608, 608, 1216, 1216, 2432, 2432, 4864};
    static const int NTs[8]    = {2, 2, 4, 4, 8, 8, 16, 16};
    static const int WPtot[8]  = {3072, 19456, 38912, 77824, 155648, 311296, 622592, 1245184};

    hipMemsetAsync(st, 0, 16400, stream);

    cast_x<<<dim3(641, 4), 256, 0, stream>>>(x, P, 40962);
    for (int j = 0; j < 8; ++j)
        prepack_w<<<(WPtot[j] + 255) / 256, 256, 0, stream>>>(W[j], WP + wp_off[j],
                                                              KCs[j], NTs[j], WPtot[j]);

    const float iN1 = 1.f / (40962.f * 4.f);
    const float iN2 = 1.f / (10242.f * 4.f);
    const float iN3 = 1.f / (2562.f * 4.f);
    const float iN4 = 1.f / (642.f * 4.f);

    // ---- Level 1 (V=40962) ----
    conv1_mfma<<<2561, 256, 0, stream>>>(P, n0, WP + wp_off[0], Y, 40962);
    stats_kernel<32><<<120, 256, 0, stream>>>(Y, st + 0 * 512, 163848);
    finalize_kernel<32><<<5121, 256, 0, stream>>>(Y, st + 0 * 512, G[0], E[0], iN1, Q, 1310784);
    conv_mfma<32, 32, 2><<<2561, 256, 0, stream>>>(Q, n0, WP + wp_off[1], Y, 40962);
    stats_kernel<32><<<120, 256, 0, stream>>>(Y, st + 1 * 512, 163848);
    finalize_kernel<32><<<5121, 256, 0, stream>>>(Y, st + 1 * 512, G[1], E[1], iN1, P, 1310784);
    pool_kernel<32><<<dim3(321, 4), 256, 0, stream>>>(P, n0, Q, 40962, 10242);
    // ---- Level 2 (V=10242) ----
    conv_mfma<32, 64, 4><<<641, 256, 0, stream>>>(Q, n1, WP + wp_off[2], Y, 10242);
    stats_kernel<64><<<120, 256, 0, stream>>>(Y, st + 2 * 512, 40968);
    finalize_kernel<64><<<2561, 256, 0, stream>>>(Y, st + 2 * 512, G[2], E[2], iN2, P, 655488);
    conv_mfma<64, 64, 4><<<641, 256, 0, stream>>>(P, n1, WP + wp_off[3], Y, 10242);
    stats_kernel<64><<<120, 256, 0, stream>>>(Y, st + 3 * 512, 40968);
    finalize_kernel<64><<<2561, 256, 0, stream>>>(Y, st + 3 * 512, G[3], E[3], iN2, Q, 655488);
    pool_kernel<64><<<dim3(161, 4), 256, 0, stream>>>(Q, n1, P, 10242, 2562);
    // ---- Level 3 (V=2562) ----
    conv_mfma<64, 128, 4><<<322, 256, 0, stream>>>(P, n2, WP + wp_off[4], Y, 2562);
    stats_kernel<128><<<120, 256, 0, stream>>>(Y, st + 4 * 512, 10248);
    finalize_kernel<128><<<1281, 256, 0, stream>>>(Y, st + 4 * 512, G[4], E[4], iN3, Q, 327936);
    conv_mfma<128, 128, 4><<<322, 256, 0, stream>>>(Q, n2, WP + wp_off[5], Y, 2562);
    stats_kernel<128><<<120, 256, 0, stream>>>(Y, st + 5 * 512, 10248);
    finalize_kernel<128><<<1281, 256, 0, stream>>>(Y, st + 5 * 512, G[5], E[5], iN3, P, 327936);
    pool_kernel<128><<<dim3(81, 4), 256, 0, stream>>>(P, n2, Q, 2562, 642);
    // ---- Level 4 (V=642) ----
    conv_mfma<128, 256, 4><<<164, 256, 0, stream>>>(Q, n3, WP + wp_off[6], Y, 642);
    stats_kernel<256><<<120, 256, 0, stream>>>(Y, st + 6 * 512, 2568);
    finalize_kernel<256><<<642, 256, 0, stream>>>(Y, st + 6 * 512, G[6], E[6], iN4, P, 164352);
    conv_mfma<256, 256, 4><<<164, 256, 0, stream>>>(P, n3, WP + wp_off[7], Y, 642);
    stats_kernel<256><<<120, 256, 0, stream>>>(Y, st + 7 * 512, 2568);
    // ---- FC ----
    fc_partial<<<128, 256, 0, stream>>>(Y, wfc, st + 7 * 512, G[7], E[7], iN4, fcacc);
    fc_finalize<<<1, 64, 0, stream>>>(fcacc, m, wm, bm, wfc, bfc, (float*)d_out);
}